// Round 1
// baseline (944.432 us; speedup 1.0000x reference)
//
#include <hip/hip_runtime.h>
#include <math.h>

#define NN 64
#define TTOK 577
#define CC 768
#define KK 64
#define NT (NN * TTOK)   // 36928

static constexpr float EPSF = 1e-12f;

// ---------------------------------------------------------------------------
// Kernel A: per-token sumsq + logits GEMM + softmax.
// 16 tokens per block, 256 threads. Writes a' = softmax*invnorm as [nt][k]
// (t-major), and token norm [nt].
// ---------------------------------------------------------------------------
__global__ __launch_bounds__(256) void ka_token_kernel(
    const float* __restrict__ grids,
    const float* __restrict__ conv_w,
    const float* __restrict__ conv_b,
    float* __restrict__ ws_a,
    float* __restrict__ ws_norm)
{
    __shared__ float xs[16 * 772];   // 16 tokens x 768, row stride 772 (bank pad)
    const int tid = threadIdx.x;
    const int tokbase = blockIdx.x << 4;

    // ---- stage 16 tokens (coalesced float4), transpose-free ----
    {
        const float4* g4 = reinterpret_cast<const float4*>(grids) + (size_t)tokbase * 192;
        #pragma unroll
        for (int j = 0; j < 12; ++j) {
            int f = tid + (j << 8);          // [0, 3072)
            int tk = f / 192;
            int c4 = f - tk * 192;
            *reinterpret_cast<float4*>(&xs[tk * 772 + (c4 << 2)]) = g4[f];
        }
    }
    __syncthreads();

    const int token = tid >> 4;   // 0..15
    const int sub   = tid & 15;   // 0..15

    // ---- sumsq over this token's slice c = sub*48 .. +47 ----
    float ss = 0.f;
    {
        const float4* p = reinterpret_cast<const float4*>(&xs[token * 772 + sub * 48]);
        #pragma unroll
        for (int j = 0; j < 12; ++j) {
            float4 v = p[j];
            ss += v.x * v.x + v.y * v.y + v.z * v.z + v.w * v.w;
        }
    }
    #pragma unroll
    for (int m = 1; m < 16; m <<= 1) ss += __shfl_xor(ss, m);
    const float nrm = sqrtf(ss);
    const float inv = 1.0f / fmaxf(nrm, EPSF);
    if (sub == 0) ws_norm[tokbase + token] = nrm;

    // ---- logits: k = 4*sub + kk, dot over C with raw x, scale by inv ----
    float acc[4] = {0.f, 0.f, 0.f, 0.f};
    const float4* xr = reinterpret_cast<const float4*>(&xs[token * 772]);
    const float4* w4 = reinterpret_cast<const float4*>(conv_w);
    const int k0 = sub << 2;
    #pragma unroll 2
    for (int c4 = 0; c4 < 192; ++c4) {
        float4 xv = xr[c4];
        #pragma unroll
        for (int kk = 0; kk < 4; ++kk) {
            float4 wv = w4[(size_t)(k0 + kk) * 192 + c4];
            acc[kk] = fmaf(xv.x, wv.x,
                      fmaf(xv.y, wv.y,
                      fmaf(xv.z, wv.z,
                      fmaf(xv.w, wv.w, acc[kk]))));
        }
    }

    float lg[4];
    #pragma unroll
    for (int kk = 0; kk < 4; ++kk) lg[kk] = acc[kk] * inv + conv_b[k0 + kk];

    // ---- softmax over 64 k spread across 16 lanes x 4 regs ----
    float mx = fmaxf(fmaxf(lg[0], lg[1]), fmaxf(lg[2], lg[3]));
    #pragma unroll
    for (int m = 1; m < 16; m <<= 1) mx = fmaxf(mx, __shfl_xor(mx, m));
    float e[4];
    float s = 0.f;
    #pragma unroll
    for (int kk = 0; kk < 4; ++kk) { e[kk] = __expf(lg[kk] - mx); s += e[kk]; }
    #pragma unroll
    for (int m = 1; m < 16; m <<= 1) s += __shfl_xor(s, m);

    const float rs = inv / s;   // a' = (e/s) * invnorm
    float4 ov;
    ov.x = e[0] * rs; ov.y = e[1] * rs; ov.z = e[2] * rs; ov.w = e[3] * rs;
    *reinterpret_cast<float4*>(ws_a + (size_t)(tokbase + token) * 64 + k0) = ov;
}

// ---------------------------------------------------------------------------
// Kernel B: per (n, c-tile of 64): P[64k x 64c] = sum_t a'[t][k] * grids[t][c]
// then subtract asum[k]*centroid[k][c]. 256 threads, 4x4 microtile.
// ---------------------------------------------------------------------------
__global__ __launch_bounds__(256) void kb_vlad_kernel(
    const float* __restrict__ grids,
    const float* __restrict__ ws_a,
    const float* __restrict__ ws_norm,
    const float* __restrict__ centroids,
    float* __restrict__ out)
{
    __shared__ float a_s[32 * 64];      // [t][k]
    __shared__ float g_s[32 * 64];      // [t][c]
    __shared__ float asum_red[4 * 64];
    __shared__ float asum_s[64];

    const int tid = threadIdx.x;
    const int n  = blockIdx.x / 12;
    const int c0 = (blockIdx.x - n * 12) << 6;
    const size_t nt0 = (size_t)n * TTOK;

    // ---- asum[k] = sum_t a[k,t] = sum_t a'[t][k] * norm[t] ----
    {
        const int k = tid & 63, q = tid >> 6;
        float s = 0.f;
        for (int t = q; t < TTOK; t += 4)
            s += ws_a[(nt0 + t) * 64 + k] * ws_norm[nt0 + t];
        asum_red[(q << 6) + k] = s;
    }
    __syncthreads();
    if (tid < 64)
        asum_s[tid] = asum_red[tid] + asum_red[64 + tid] + asum_red[128 + tid] + asum_red[192 + tid];
    __syncthreads();

    const int ty = tid >> 4;   // k group
    const int tx = tid & 15;   // c group
    float accr[4][4] = {};

    for (int t0 = 0; t0 < TTOK; t0 += 32) {
        const int cs = (TTOK - t0) < 32 ? (TTOK - t0) : 32;
        // stage a' chunk [cs][64]
        {
            const float4* src = reinterpret_cast<const float4*>(ws_a + (nt0 + t0) * 64);
            float4* dst = reinterpret_cast<float4*>(a_s);
            for (int f = tid; f < cs * 16; f += 256) dst[f] = src[f];
        }
        // stage grids chunk [cs][64] from column tile c0
        {
            float4* dst = reinterpret_cast<float4*>(g_s);
            for (int f = tid; f < cs * 16; f += 256) {
                int tt = f >> 4, cc = f & 15;
                dst[f] = *reinterpret_cast<const float4*>(
                    grids + (nt0 + t0 + tt) * CC + c0 + (cc << 2));
            }
        }
        __syncthreads();

        for (int tt = 0; tt < cs; ++tt) {
            float4 av4 = *reinterpret_cast<const float4*>(&a_s[(tt << 6) + (ty << 2)]);
            float4 gv4 = *reinterpret_cast<const float4*>(&g_s[(tt << 6) + (tx << 2)]);
            float av[4] = {av4.x, av4.y, av4.z, av4.w};
            float gv[4] = {gv4.x, gv4.y, gv4.z, gv4.w};
            #pragma unroll
            for (int i = 0; i < 4; ++i)
                #pragma unroll
                for (int j = 0; j < 4; ++j)
                    accr[i][j] = fmaf(av[i], gv[j], accr[i][j]);
        }
        __syncthreads();
    }

    // ---- epilogue: subtract asum*centroid, write p ----
    #pragma unroll
    for (int i = 0; i < 4; ++i) {
        const int k = (ty << 2) + i;
        const float as = asum_s[k];
        float4 cv = *reinterpret_cast<const float4*>(centroids + (size_t)k * CC + c0 + (tx << 2));
        float4 o;
        o.x = accr[i][0] - as * cv.x;
        o.y = accr[i][1] - as * cv.y;
        o.z = accr[i][2] - as * cv.z;
        o.w = accr[i][3] - as * cv.w;
        *reinterpret_cast<float4*>(out + ((size_t)(n * 64 + k)) * CC + c0 + (tx << 2)) = o;
    }
}

// ---------------------------------------------------------------------------
// Kernel C: per (n,k): scale row by 1/(max(||row||,eps)*8)  (global norm = 8)
// ---------------------------------------------------------------------------
__global__ __launch_bounds__(64) void kc_norm_kernel(float* __restrict__ out)
{
    float4* p = reinterpret_cast<float4*>(out) + (size_t)blockIdx.x * 192;
    const int l = threadIdx.x;
    float4 v0 = p[l];
    float4 v1 = p[l + 64];
    float4 v2 = p[l + 128];
    float ss = v0.x * v0.x + v0.y * v0.y + v0.z * v0.z + v0.w * v0.w
             + v1.x * v1.x + v1.y * v1.y + v1.z * v1.z + v1.w * v1.w
             + v2.x * v2.x + v2.y * v2.y + v2.z * v2.z + v2.w * v2.w;
    #pragma unroll
    for (int m = 1; m < 64; m <<= 1) ss += __shfl_xor(ss, m);
    const float sc = 0.125f / fmaxf(sqrtf(ss), EPSF);
    v0.x *= sc; v0.y *= sc; v0.z *= sc; v0.w *= sc;
    v1.x *= sc; v1.y *= sc; v1.z *= sc; v1.w *= sc;
    v2.x *= sc; v2.y *= sc; v2.z *= sc; v2.w *= sc;
    p[l] = v0;
    p[l + 64] = v1;
    p[l + 128] = v2;
}

extern "C" void kernel_launch(void* const* d_in, const int* in_sizes, int n_in,
                              void* d_out, int out_size, void* d_ws, size_t ws_size,
                              hipStream_t stream)
{
    const float* grids     = (const float*)d_in[0];
    const float* conv_w    = (const float*)d_in[1];
    const float* conv_b    = (const float*)d_in[2];
    const float* centroids = (const float*)d_in[3];
    float* out = (float*)d_out;

    float* ws_a    = (float*)d_ws;                 // NT*64 floats (9.45 MB)
    float* ws_norm = ws_a + (size_t)NT * 64;       // NT floats

    hipLaunchKernelGGL(ka_token_kernel, dim3(NT / 16), dim3(256), 0, stream,
                       grids, conv_w, conv_b, ws_a, ws_norm);
    hipLaunchKernelGGL(kb_vlad_kernel, dim3(NN * 12), dim3(256), 0, stream,
                       grids, ws_a, ws_norm, centroids, out);
    hipLaunchKernelGGL(kc_norm_kernel, dim3(NN * KK), dim3(64), 0, stream, out);
}

// Round 2
// 84.327 us; speedup vs baseline: 11.1996x; 11.1996x over previous
//
#include <hip/hip_runtime.h>
#include <math.h>

#define TT 577          // real tokens per n
#define TP 640          // padded tokens per n (multiple of 32, >= TT)
#define CCH 768         // channels
#define KR 64           // regions
#define NB 64           // batch

typedef __attribute__((ext_vector_type(8))) short bf16x8;
typedef __attribute__((ext_vector_type(8))) unsigned short ushort8;
typedef __attribute__((ext_vector_type(4))) float f32x4;

static constexpr float EPSF = 1e-12f;

// RNE float -> bf16 bits (finite inputs only)
static __device__ inline unsigned short f2bf(float f) {
    union { float f; unsigned int u; } v; v.f = f;
    unsigned int r = (v.u + 0x7FFFu + ((v.u >> 16) & 1u)) >> 16;
    return (unsigned short)r;
}
static __device__ inline float bf2f(unsigned short b) {
    union { unsigned int u; float f; } v; v.u = ((unsigned int)b) << 16;
    return v.f;
}

// ---------------------------------------------------------------------------
// Kernel 1: GEMM1 (logits) + token norms + softmax + transposed a' write.
// Grid: 64 n x 10 t-blocks of 64 tokens. Block 256 thr = 4 waves x 16 tokens.
// Writes ws_a[n][kr][TP] (bf16, t-contiguous, zero-padded) + ws_norm[n][TP].
// ---------------------------------------------------------------------------
__global__ __launch_bounds__(256) void k_logits(
    const float* __restrict__ grids,
    const float* __restrict__ conv_w,
    const float* __restrict__ conv_b,
    unsigned short* __restrict__ ws_a,
    float* __restrict__ ws_norm)
{
    __shared__ __align__(16) unsigned short Wl[KR * 136];      // W chunk [64][128], stride 136
    __shared__ __align__(16) unsigned short Abuf[4][KR * 24];  // per-wave [64 kr][16 t], stride 24

    const int tid  = threadIdx.x;
    const int lane = tid & 63;
    const int w    = tid >> 6;
    const int n    = blockIdx.x / 10;
    const int tb   = (blockIdx.x - n * 10) << 6;
    const int t0w  = tb + (w << 4);

    const int lr = lane & 15;
    const int lg = lane >> 4;

    const int tokA = t0w + lr;
    const bool validA = (tokA < TT);
    const float* gsrc = grids + ((size_t)n * TT + tokA) * CCH + (lg << 3);

    f32x4 acc[4] = {};
    float ss = 0.f;

    for (int c0 = 0; c0 < CCH; c0 += 128) {
        #pragma unroll
        for (int it = 0; it < 4; ++it) {
            int f = tid + (it << 8);
            int kr = f >> 4;
            int c8 = (f & 15) << 3;
            const float* src = conv_w + (size_t)kr * CCH + c0 + c8;
            float4 v0 = *reinterpret_cast<const float4*>(src);
            float4 v1 = *reinterpret_cast<const float4*>(src + 4);
            unsigned short* dst = &Wl[kr * 136 + c8];
            dst[0]=f2bf(v0.x); dst[1]=f2bf(v0.y); dst[2]=f2bf(v0.z); dst[3]=f2bf(v0.w);
            dst[4]=f2bf(v1.x); dst[5]=f2bf(v1.y); dst[6]=f2bf(v1.z); dst[7]=f2bf(v1.w);
        }
        __syncthreads();

        #pragma unroll
        for (int s = 0; s < 4; ++s) {
            float a8[8];
            if (validA) {
                float4 u0 = *reinterpret_cast<const float4*>(gsrc + c0 + (s << 5));
                float4 u1 = *reinterpret_cast<const float4*>(gsrc + c0 + (s << 5) + 4);
                a8[0]=u0.x; a8[1]=u0.y; a8[2]=u0.z; a8[3]=u0.w;
                a8[4]=u1.x; a8[5]=u1.y; a8[6]=u1.z; a8[7]=u1.w;
            } else {
                #pragma unroll
                for (int j = 0; j < 8; ++j) a8[j] = 0.f;
            }
            bf16x8 afrag;
            #pragma unroll
            for (int j = 0; j < 8; ++j) {
                ss = fmaf(a8[j], a8[j], ss);
                ((unsigned short*)&afrag)[j] = f2bf(a8[j]);
            }
            const int cl = (s << 5) + (lg << 3);
            #pragma unroll
            for (int rt = 0; rt < 4; ++rt) {
                bf16x8 bfrag = *reinterpret_cast<const bf16x8*>(&Wl[(rt*16 + lr)*136 + cl]);
                acc[rt] = __builtin_amdgcn_mfma_f32_16x16x32_bf16(afrag, bfrag, acc[rt], 0, 0, 0);
            }
        }
        __syncthreads();
    }

    ss += __shfl_xor(ss, 16);
    ss += __shfl_xor(ss, 32);
    const float nrm = sqrtf(ss);
    const float inv = 1.0f / fmaxf(nrm, EPSF);
    if (lane < 16) ws_norm[n * TP + t0w + lane] = nrm;

    float b_[4];
    #pragma unroll
    for (int rt = 0; rt < 4; ++rt) b_[rt] = conv_b[rt*16 + lr];

    float invT[4];
    #pragma unroll
    for (int reg = 0; reg < 4; ++reg) invT[reg] = __shfl(inv, (lg << 2) + reg);

    float lgt[4][4], mx[4];
    #pragma unroll
    for (int reg = 0; reg < 4; ++reg) {
        float m = -1e30f;
        #pragma unroll
        for (int rt = 0; rt < 4; ++rt) {
            lgt[rt][reg] = fmaf(acc[rt][reg], invT[reg], b_[rt]);
            m = fmaxf(m, lgt[rt][reg]);
        }
        mx[reg] = m;
    }
    #pragma unroll
    for (int msk = 1; msk < 16; msk <<= 1) {
        #pragma unroll
        for (int reg = 0; reg < 4; ++reg) mx[reg] = fmaxf(mx[reg], __shfl_xor(mx[reg], msk));
    }
    float ex[4][4], sm[4] = {0.f, 0.f, 0.f, 0.f};
    #pragma unroll
    for (int rt = 0; rt < 4; ++rt) {
        #pragma unroll
        for (int reg = 0; reg < 4; ++reg) {
            ex[rt][reg] = __expf(lgt[rt][reg] - mx[reg]);
            sm[reg] += ex[rt][reg];
        }
    }
    #pragma unroll
    for (int msk = 1; msk < 16; msk <<= 1) {
        #pragma unroll
        for (int reg = 0; reg < 4; ++reg) sm[reg] += __shfl_xor(sm[reg], msk);
    }

    #pragma unroll
    for (int reg = 0; reg < 4; ++reg) {
        const int trow = (lg << 2) + reg;
        const bool vt = (t0w + trow) < TT;
        const float scale = vt ? (invT[reg] / sm[reg]) : 0.f;
        #pragma unroll
        for (int rt = 0; rt < 4; ++rt)
            Abuf[w][(rt*16 + lr)*24 + trow] = f2bf(ex[rt][reg] * scale);
    }
    __syncthreads();

    {
        ushort8 r0 = *reinterpret_cast<const ushort8*>(&Abuf[w][lane * 24]);
        ushort8 r1 = *reinterpret_cast<const ushort8*>(&Abuf[w][lane * 24 + 8]);
        unsigned short* dst = ws_a + ((size_t)n * KR + lane) * TP + t0w;
        *reinterpret_cast<ushort8*>(dst)     = r0;
        *reinterpret_cast<ushort8*>(dst + 8) = r1;
    }
}

// ---------------------------------------------------------------------------
// Kernel 2: GEMM2 (VLAD) per (n, 192-c quarter), minus asum*centroid.
// ---------------------------------------------------------------------------
__global__ __launch_bounds__(256) void k_vlad(
    const float* __restrict__ grids,
    const unsigned short* __restrict__ ws_a,
    const float* __restrict__ ws_norm,
    const float* __restrict__ centroids,
    float* __restrict__ out)
{
    __shared__ __align__(16) unsigned short Gs[32 * 196];
    __shared__ float asum_red[4][64];
    __shared__ float asum_s[64];

    const int tid  = threadIdx.x;
    const int lane = tid & 63;
    const int w    = tid >> 6;
    const int n    = blockIdx.x >> 2;
    const int cq   = (blockIdx.x & 3) * 192;

    {
        const int kr = tid & 63, q = tid >> 6;
        const unsigned short* ap = ws_a + ((size_t)n * KR + kr) * TP;
        const float* np = ws_norm + n * TP;
        float s = 0.f;
        for (int t = q * 8; t < TP; t += 32) {
            ushort8 av = *reinterpret_cast<const ushort8*>(ap + t);
            float4 n0 = *reinterpret_cast<const float4*>(np + t);
            float4 n1 = *reinterpret_cast<const float4*>(np + t + 4);
            s += bf2f(av[0])*n0.x + bf2f(av[1])*n0.y + bf2f(av[2])*n0.z + bf2f(av[3])*n0.w
               + bf2f(av[4])*n1.x + bf2f(av[5])*n1.y + bf2f(av[6])*n1.z + bf2f(av[7])*n1.w;
        }
        asum_red[q][kr] = s;
    }
    __syncthreads();
    if (tid < 64)
        asum_s[tid] = asum_red[0][tid] + asum_red[1][tid] + asum_red[2][tid] + asum_red[3][tid];

    const int lr = lane & 15;
    const int lg = lane >> 4;
    f32x4 acc[4][3] = {};

    const unsigned short* abase = ws_a + ((size_t)n * KR + lr) * TP;

    float4 stg[6];
    auto load_chunk = [&](int t0) {
        #pragma unroll
        for (int it = 0; it < 6; ++it) {
            int f = tid + (it << 8);
            int t = f / 48, c4 = (f - t * 48) << 2;
            stg[it] = make_float4(0.f, 0.f, 0.f, 0.f);
            if (t0 + t < TT)
                stg[it] = *reinterpret_cast<const float4*>(
                    grids + ((size_t)n * TT + t0 + t) * CCH + cq + c4);
        }
    };

    load_chunk(0);
    for (int t0 = 0; t0 < TT; t0 += 32) {
        __syncthreads();
        #pragma unroll
        for (int it = 0; it < 6; ++it) {
            int f = tid + (it << 8);
            int t = f / 48, c4 = (f - t * 48) << 2;
            unsigned short* dst = &Gs[t * 196 + c4];
            float4 v = stg[it];
            dst[0]=f2bf(v.x); dst[1]=f2bf(v.y); dst[2]=f2bf(v.z); dst[3]=f2bf(v.w);
        }
        __syncthreads();

        if (t0 + 32 < TT) load_chunk(t0 + 32);

        bf16x8 af[4];
        #pragma unroll
        for (int rt = 0; rt < 4; ++rt)
            af[rt] = *reinterpret_cast<const bf16x8*>(abase + (size_t)rt * 16 * TP + t0 + (lg << 3));

        #pragma unroll
        for (int ct = 0; ct < 3; ++ct) {
            const int cc = w * 48 + ct * 16 + lr;
            bf16x8 bfrag;
            #pragma unroll
            for (int j = 0; j < 8; ++j)
                ((unsigned short*)&bfrag)[j] = Gs[((lg << 3) + j) * 196 + cc];
            #pragma unroll
            for (int rt = 0; rt < 4; ++rt)
                acc[rt][ct] = __builtin_amdgcn_mfma_f32_16x16x32_bf16(af[rt], bfrag, acc[rt][ct], 0, 0, 0);
        }
    }
    __syncthreads();

    #pragma unroll
    for (int rt = 0; rt < 4; ++rt) {
        #pragma unroll
        for (int reg = 0; reg < 4; ++reg) {
            const int kr = rt * 16 + (lg << 2) + reg;
            const float as = asum_s[kr];
            #pragma unroll
            for (int ct = 0; ct < 3; ++ct) {
                const int c = cq + w * 48 + ct * 16 + lr;
                out[((size_t)n * KR + kr) * CCH + c] =
                    acc[rt][ct][reg] - as * centroids[(size_t)kr * CCH + c];
            }
        }
    }
}

__global__ __launch_bounds__(64) void kc_norm_kernel(float* __restrict__ out)
{
    float4* p = reinterpret_cast<float4*>(out) + (size_t)blockIdx.x * 192;
    const int l = threadIdx.x;
    float4 v0 = p[l];
    float4 v1 = p[l + 64];
    float4 v2 = p[l + 128];
    float ss = v0.x*v0.x + v0.y*v0.y + v0.z*v0.z + v0.w*v0.w
             + v1.x*v1.x + v1.y*v1.y + v1.z*v1.z + v1.w*v1.w
             + v2.x*v2.x + v2.y*v2.y + v2.z*v2.z + v2.w*v2.w;
    #pragma unroll
    for (int m = 1; m < 64; m <<= 1) ss += __shfl_xor(ss, m);
    const float sc = 0.125f / fmaxf(sqrtf(ss), EPSF);
    v0.x*=sc; v0.y*=sc; v0.z*=sc; v0.w*=sc;
    v1.x*=sc; v1.y*=sc; v1.z*=sc; v1.w*=sc;
    v2.x*=sc; v2.y*=sc; v2.z*=sc; v2.w*=sc;
    p[l] = v0;
    p[l + 64] = v1;
    p[l + 128] = v2;
}

extern "C" void kernel_launch(void* const* d_in, const int* in_sizes, int n_in,
                              void* d_out, int out_size, void* d_ws, size_t ws_size,
                              hipStream_t stream)
{
    const float* grids     = (const float*)d_in[0];
    const float* conv_w    = (const float*)d_in[1];
    const float* conv_b    = (const float*)d_in[2];
    const float* centroids = (const float*)d_in[3];
    float* out = (float*)d_out;

    unsigned short* ws_a = (unsigned short*)d_ws;
    float* ws_norm = (float*)((char*)d_ws + (size_t)NB * KR * TP * 2);

    hipLaunchKernelGGL(k_logits, dim3(NB * 10), dim3(256), 0, stream,
                       grids, conv_w, conv_b, ws_a, ws_norm);
    hipLaunchKernelGGL(k_vlad, dim3(NB * 4), dim3(256), 0, stream,
                       grids, ws_a, ws_norm, centroids, out);
    hipLaunchKernelGGL(kc_norm_kernel, dim3(NB * KR), dim3(64), 0, stream, out);
}

// Round 3
// 82.468 us; speedup vs baseline: 11.4521x; 1.0225x over previous
//
#include <hip/hip_runtime.h>
#include <math.h>

#define TT 577          // real tokens per n
#define TP 640          // padded tokens per n (multiple of 32, >= TT)
#define CCH 768         // channels
#define KR 64           // regions
#define NB 64           // batch

typedef __attribute__((ext_vector_type(8))) short bf16x8;
typedef __attribute__((ext_vector_type(8))) unsigned short ushort8;
typedef __attribute__((ext_vector_type(4))) float f32x4;

static constexpr float EPSF = 1e-12f;

// RNE float -> bf16 bits (finite inputs only)
static __device__ inline unsigned short f2bf(float f) {
    union { float f; unsigned int u; } v; v.f = f;
    return (unsigned short)((v.u + 0x7FFFu + ((v.u >> 16) & 1u)) >> 16);
}
static __device__ inline float bf2f(unsigned short b) {
    union { unsigned int u; float f; } v; v.u = ((unsigned int)b) << 16;
    return v.f;
}

// ---------------------------------------------------------------------------
// Kernel 1: GEMM1 (logits) + token norms + softmax + transposed a' write.
// Grid: 64 n x 10 t-blocks of 64 tokens. Block 256 thr = 4 waves x 16 tokens.
// W chunks (128 c) double-buffered in LDS: 1 barrier/chunk. Abuf aliased on Wl.
// ---------------------------------------------------------------------------
__global__ __launch_bounds__(256) void k_logits(
    const float* __restrict__ grids,
    const float* __restrict__ conv_w,
    const float* __restrict__ conv_b,
    unsigned short* __restrict__ ws_a,
    float* __restrict__ ws_norm)
{
    __shared__ __align__(16) unsigned short Wl[2][KR * 136];

    const int tid  = threadIdx.x;
    const int lane = tid & 63;
    const int w    = tid >> 6;
    const int n    = blockIdx.x / 10;
    const int tb   = (blockIdx.x - n * 10) << 6;
    const int t0w  = tb + (w << 4);

    const int lr = lane & 15;
    const int lg = lane >> 4;

    const int tokA = t0w + lr;
    const bool validA = (tokA < TT);
    const float* gsrc = grids + ((size_t)n * TT + tokA) * CCH + (lg << 3);

    float4 wreg[4][2];
    auto load_w = [&](int c0) {
        #pragma unroll
        for (int it = 0; it < 4; ++it) {
            int f = tid + (it << 8);
            int kr = f >> 4, c8 = (f & 15) << 3;
            const float* src = conv_w + (size_t)kr * CCH + c0 + c8;
            wreg[it][0] = *reinterpret_cast<const float4*>(src);
            wreg[it][1] = *reinterpret_cast<const float4*>(src + 4);
        }
    };
    auto store_w = [&](int buf) {
        #pragma unroll
        for (int it = 0; it < 4; ++it) {
            int f = tid + (it << 8);
            int kr = f >> 4, c8 = (f & 15) << 3;
            ushort8 o;
            o[0] = f2bf(wreg[it][0].x); o[1] = f2bf(wreg[it][0].y);
            o[2] = f2bf(wreg[it][0].z); o[3] = f2bf(wreg[it][0].w);
            o[4] = f2bf(wreg[it][1].x); o[5] = f2bf(wreg[it][1].y);
            o[6] = f2bf(wreg[it][1].z); o[7] = f2bf(wreg[it][1].w);
            *reinterpret_cast<ushort8*>(&Wl[buf][kr * 136 + c8]) = o;
        }
    };

    f32x4 acc[4] = {};
    float ss = 0.f;

    load_w(0);
    store_w(0);
    __syncthreads();

    for (int ch = 0; ch < 6; ++ch) {
        if (ch < 5) {
            load_w((ch + 1) << 7);
            store_w((ch + 1) & 1);
        }
        const int c0 = ch << 7;
        const unsigned short* Wb = Wl[ch & 1];

        #pragma unroll
        for (int s = 0; s < 4; ++s) {
            float a8[8];
            if (validA) {
                float4 u0 = *reinterpret_cast<const float4*>(gsrc + c0 + (s << 5));
                float4 u1 = *reinterpret_cast<const float4*>(gsrc + c0 + (s << 5) + 4);
                a8[0]=u0.x; a8[1]=u0.y; a8[2]=u0.z; a8[3]=u0.w;
                a8[4]=u1.x; a8[5]=u1.y; a8[6]=u1.z; a8[7]=u1.w;
            } else {
                #pragma unroll
                for (int j = 0; j < 8; ++j) a8[j] = 0.f;
            }
            bf16x8 afrag;
            #pragma unroll
            for (int j = 0; j < 8; ++j) {
                ss = fmaf(a8[j], a8[j], ss);
                ((unsigned short*)&afrag)[j] = f2bf(a8[j]);
            }
            const int cl = (s << 5) + (lg << 3);
            #pragma unroll
            for (int rt = 0; rt < 4; ++rt) {
                bf16x8 bfrag = *reinterpret_cast<const bf16x8*>(&Wb[(rt*16 + lr)*136 + cl]);
                acc[rt] = __builtin_amdgcn_mfma_f32_16x16x32_bf16(afrag, bfrag, acc[rt], 0, 0, 0);
            }
        }
        __syncthreads();
    }

    ss += __shfl_xor(ss, 16);
    ss += __shfl_xor(ss, 32);
    const float nrm = sqrtf(ss);
    const float inv = 1.0f / fmaxf(nrm, EPSF);
    if (lane < 16) ws_norm[n * TP + t0w + lane] = nrm;

    float b_[4];
    #pragma unroll
    for (int rt = 0; rt < 4; ++rt) b_[rt] = conv_b[rt*16 + lr];

    float invT[4];
    #pragma unroll
    for (int reg = 0; reg < 4; ++reg) invT[reg] = __shfl(inv, (lg << 2) + reg);

    float lgt[4][4], mx[4];
    #pragma unroll
    for (int reg = 0; reg < 4; ++reg) {
        float m = -1e30f;
        #pragma unroll
        for (int rt = 0; rt < 4; ++rt) {
            lgt[rt][reg] = fmaf(acc[rt][reg], invT[reg], b_[rt]);
            m = fmaxf(m, lgt[rt][reg]);
        }
        mx[reg] = m;
    }
    #pragma unroll
    for (int msk = 1; msk < 16; msk <<= 1) {
        #pragma unroll
        for (int reg = 0; reg < 4; ++reg) mx[reg] = fmaxf(mx[reg], __shfl_xor(mx[reg], msk));
    }
    float ex[4][4], sm[4] = {0.f, 0.f, 0.f, 0.f};
    #pragma unroll
    for (int rt = 0; rt < 4; ++rt) {
        #pragma unroll
        for (int reg = 0; reg < 4; ++reg) {
            ex[rt][reg] = __expf(lgt[rt][reg] - mx[reg]);
            sm[reg] += ex[rt][reg];
        }
    }
    #pragma unroll
    for (int msk = 1; msk < 16; msk <<= 1) {
        #pragma unroll
        for (int reg = 0; reg < 4; ++reg) sm[reg] += __shfl_xor(sm[reg], msk);
    }

    unsigned short* Abuf = &Wl[0][0] + (size_t)w * KR * 24;
    #pragma unroll
    for (int reg = 0; reg < 4; ++reg) {
        const int trow = (lg << 2) + reg;
        const bool vt = (t0w + trow) < TT;
        const float scale = vt ? (invT[reg] / sm[reg]) : 0.f;
        #pragma unroll
        for (int rt = 0; rt < 4; ++rt)
            Abuf[(rt*16 + lr)*24 + trow] = f2bf(ex[rt][reg] * scale);
    }
    __syncthreads();

    {
        ushort8 r0 = *reinterpret_cast<const ushort8*>(&Abuf[lane * 24]);
        ushort8 r1 = *reinterpret_cast<const ushort8*>(&Abuf[lane * 24 + 8]);
        unsigned short* dst = ws_a + ((size_t)n * KR + lane) * TP + t0w;
        *reinterpret_cast<ushort8*>(dst)     = r0;
        *reinterpret_cast<ushort8*>(dst + 8) = r1;
    }
}

// ---------------------------------------------------------------------------
// Kernel 2: GEMM2 (VLAD): grid = n x 12 c-tiles (64 c) = 768 blocks, 4 waves,
// wave tile 64kr x 16c. No LDS staging; 1-deep fragment prefetch.
// ---------------------------------------------------------------------------
__global__ __launch_bounds__(256) void k_vlad(
    const float* __restrict__ grids,
    const unsigned short* __restrict__ ws_a,
    const float* __restrict__ ws_norm,
    const float* __restrict__ centroids,
    float* __restrict__ out)
{
    __shared__ float asum_red[4][64];
    __shared__ float asum_s[64];

    const int tid  = threadIdx.x;
    const int lane = tid & 63;
    const int w    = tid >> 6;
    const int n    = blockIdx.x / 12;
    const int c0   = (blockIdx.x - n * 12) << 6;
    const int lr   = lane & 15;
    const int lg   = lane >> 4;

    {
        const int kr = tid & 63, q = tid >> 6;
        const unsigned short* ap = ws_a + ((size_t)n * KR + kr) * TP;
        const float* np = ws_norm + n * TP;
        float s = 0.f;
        for (int t = q * 8; t < TP; t += 32) {
            ushort8 av = *reinterpret_cast<const ushort8*>(ap + t);
            float4 n0 = *reinterpret_cast<const float4*>(np + t);
            float4 n1 = *reinterpret_cast<const float4*>(np + t + 4);
            s += bf2f(av[0])*n0.x + bf2f(av[1])*n0.y + bf2f(av[2])*n0.z + bf2f(av[3])*n0.w
               + bf2f(av[4])*n1.x + bf2f(av[5])*n1.y + bf2f(av[6])*n1.z + bf2f(av[7])*n1.w;
        }
        asum_red[q][kr] = s;
    }
    __syncthreads();
    if (tid < 64)
        asum_s[tid] = asum_red[0][tid] + asum_red[1][tid] + asum_red[2][tid] + asum_red[3][tid];
    __syncthreads();

    const int c = c0 + (w << 4) + lr;
    const unsigned short* abase = ws_a + ((size_t)n * KR + lr) * TP + (lg << 3);
    const float* gb = grids + (size_t)n * TT * CCH + c;

    auto load_frags = [&](int t0, bf16x8* af, bf16x8& bfv) {
        #pragma unroll
        for (int rt = 0; rt < 4; ++rt)
            af[rt] = *reinterpret_cast<const bf16x8*>(abase + (size_t)rt * 16 * TP + t0);
        const int tb2 = t0 + (lg << 3);
        if (t0 + 32 <= TT) {
            #pragma unroll
            for (int j = 0; j < 8; ++j)
                ((unsigned short*)&bfv)[j] = f2bf(gb[(size_t)(tb2 + j) * CCH]);
        } else {
            #pragma unroll
            for (int j = 0; j < 8; ++j) {
                float v = (tb2 + j < TT) ? gb[(size_t)(tb2 + j) * CCH] : 0.f;
                ((unsigned short*)&bfv)[j] = f2bf(v);
            }
        }
    };

    f32x4 acc[4] = {};
    bf16x8 afA[4], afB[4];
    bf16x8 bfA, bfB;

    load_frags(0, afA, bfA);
    #pragma unroll 2
    for (int t0 = 0; t0 < TT; t0 += 64) {
        // even sub-step: compute A-set, prefetch into B-set
        if (t0 + 32 < TT) load_frags(t0 + 32, afB, bfB);
        #pragma unroll
        for (int rt = 0; rt < 4; ++rt)
            acc[rt] = __builtin_amdgcn_mfma_f32_16x16x32_bf16(afA[rt], bfA, acc[rt], 0, 0, 0);
        if (t0 + 32 >= TT) break;
        // odd sub-step: compute B-set, prefetch into A-set
        if (t0 + 64 < TT) load_frags(t0 + 64, afA, bfA);
        #pragma unroll
        for (int rt = 0; rt < 4; ++rt)
            acc[rt] = __builtin_amdgcn_mfma_f32_16x16x32_bf16(afB[rt], bfB, acc[rt], 0, 0, 0);
    }

    #pragma unroll
    for (int rt = 0; rt < 4; ++rt) {
        #pragma unroll
        for (int reg = 0; reg < 4; ++reg) {
            const int kr = rt * 16 + (lg << 2) + reg;
            out[((size_t)n * KR + kr) * CCH + c] =
                acc[rt][reg] - asum_s[kr] * centroids[(size_t)kr * CCH + c];
        }
    }
}

// ---------------------------------------------------------------------------
// Kernel 3: per (n,kr) row normalize; global L2 norm of 64 unit rows = 8.
// ---------------------------------------------------------------------------
__global__ __launch_bounds__(64) void kc_norm_kernel(float* __restrict__ out)
{
    float4* p = reinterpret_cast<float4*>(out) + (size_t)blockIdx.x * 192;
    const int l = threadIdx.x;
    float4 v0 = p[l];
    float4 v1 = p[l + 64];
    float4 v2 = p[l + 128];
    float ss = v0.x*v0.x + v0.y*v0.y + v0.z*v0.z + v0.w*v0.w
             + v1.x*v1.x + v1.y*v1.y + v1.z*v1.z + v1.w*v1.w
             + v2.x*v2.x + v2.y*v2.y + v2.z*v2.z + v2.w*v2.w;
    #pragma unroll
    for (int m = 1; m < 64; m <<= 1) ss += __shfl_xor(ss, m);
    const float sc = 0.125f / fmaxf(sqrtf(ss), EPSF);
    v0.x*=sc; v0.y*=sc; v0.z*=sc; v0.w*=sc;
    v1.x*=sc; v1.y*=sc; v1.z*=sc; v1.w*=sc;
    v2.x*=sc; v2.y*=sc; v2.z*=sc; v2.w*=sc;
    p[l] = v0;
    p[l + 64] = v1;
    p[l + 128] = v2;
}

extern "C" void kernel_launch(void* const* d_in, const int* in_sizes, int n_in,
                              void* d_out, int out_size, void* d_ws, size_t ws_size,
                              hipStream_t stream)
{
    const float* grids     = (const float*)d_in[0];
    const float* conv_w    = (const float*)d_in[1];
    const float* conv_b    = (const float*)d_in[2];
    const float* centroids = (const float*)d_in[3];
    float* out = (float*)d_out;

    unsigned short* ws_a = (unsigned short*)d_ws;
    float* ws_norm = (float*)((char*)d_ws + (size_t)NB * KR * TP * 2);

    hipLaunchKernelGGL(k_logits, dim3(NB * 10), dim3(256), 0, stream,
                       grids, conv_w, conv_b, ws_a, ws_norm);
    hipLaunchKernelGGL(k_vlad, dim3(NB * 12), dim3(256), 0, stream,
                       grids, ws_a, ws_norm, centroids, out);
    hipLaunchKernelGGL(kc_norm_kernel, dim3(NB * KR), dim3(64), 0, stream, out);
}

// Round 4
// 73.183 us; speedup vs baseline: 12.9051x; 1.1269x over previous
//
#include <hip/hip_runtime.h>
#include <math.h>

#define TT 577          // real tokens per n
#define TP 640          // padded tokens per n (multiple of 32, >= TT)
#define CCH 768         // channels
#define KR 64           // regions
#define NB 64           // batch

typedef __attribute__((ext_vector_type(8))) short bf16x8;
typedef __attribute__((ext_vector_type(8))) unsigned short ushort8;
typedef __attribute__((ext_vector_type(4))) float f32x4;

static constexpr float EPSF = 1e-12f;

// RNE float -> bf16 bits (finite inputs only)
static __device__ inline unsigned short f2bf(float f) {
    union { float f; unsigned int u; } v; v.f = f;
    return (unsigned short)((v.u + 0x7FFFu + ((v.u >> 16) & 1u)) >> 16);
}

// ---------------------------------------------------------------------------
// Kernel 1: GEMM1 (logits) + token norms + softmax + transposed a' write
// + per-block partial asum (sum over this block's 64 tokens of a[kr][t]).
// Grid: 64 n x 10 t-blocks of 64 tokens. Block 256 thr = 4 waves x 16 tokens.
// W chunks (128 c) double-buffered in LDS; Abuf aliased on Wl[0], asum LDS on Wl[1].
// ---------------------------------------------------------------------------
__global__ __launch_bounds__(256) void k_logits(
    const float* __restrict__ grids,
    const float* __restrict__ conv_w,
    const float* __restrict__ conv_b,
    unsigned short* __restrict__ ws_a,
    float* __restrict__ ws_asum)
{
    __shared__ __align__(16) unsigned short Wl[2][KR * 136];

    const int tid  = threadIdx.x;
    const int lane = tid & 63;
    const int w    = tid >> 6;
    const int n    = blockIdx.x / 10;
    const int tb   = (blockIdx.x - n * 10) << 6;
    const int t0w  = tb + (w << 4);

    const int lr = lane & 15;
    const int lg = lane >> 4;

    const int tokA = t0w + lr;
    const bool validA = (tokA < TT);
    const float* gsrc = grids + ((size_t)n * TT + tokA) * CCH + (lg << 3);

    float4 wreg[4][2];
    auto load_w = [&](int c0) {
        #pragma unroll
        for (int it = 0; it < 4; ++it) {
            int f = tid + (it << 8);
            int kr = f >> 4, c8 = (f & 15) << 3;
            const float* src = conv_w + (size_t)kr * CCH + c0 + c8;
            wreg[it][0] = *reinterpret_cast<const float4*>(src);
            wreg[it][1] = *reinterpret_cast<const float4*>(src + 4);
        }
    };
    auto store_w = [&](int buf) {
        #pragma unroll
        for (int it = 0; it < 4; ++it) {
            int f = tid + (it << 8);
            int kr = f >> 4, c8 = (f & 15) << 3;
            ushort8 o;
            o[0] = f2bf(wreg[it][0].x); o[1] = f2bf(wreg[it][0].y);
            o[2] = f2bf(wreg[it][0].z); o[3] = f2bf(wreg[it][0].w);
            o[4] = f2bf(wreg[it][1].x); o[5] = f2bf(wreg[it][1].y);
            o[6] = f2bf(wreg[it][1].z); o[7] = f2bf(wreg[it][1].w);
            *reinterpret_cast<ushort8*>(&Wl[buf][kr * 136 + c8]) = o;
        }
    };

    f32x4 acc[4] = {};
    float ss = 0.f;

    load_w(0);
    store_w(0);
    __syncthreads();

    for (int ch = 0; ch < 6; ++ch) {
        if (ch < 5) {
            load_w((ch + 1) << 7);
            store_w((ch + 1) & 1);
        }
        const int c0 = ch << 7;
        const unsigned short* Wb = Wl[ch & 1];

        #pragma unroll
        for (int s = 0; s < 4; ++s) {
            float a8[8];
            if (validA) {
                float4 u0 = *reinterpret_cast<const float4*>(gsrc + c0 + (s << 5));
                float4 u1 = *reinterpret_cast<const float4*>(gsrc + c0 + (s << 5) + 4);
                a8[0]=u0.x; a8[1]=u0.y; a8[2]=u0.z; a8[3]=u0.w;
                a8[4]=u1.x; a8[5]=u1.y; a8[6]=u1.z; a8[7]=u1.w;
            } else {
                #pragma unroll
                for (int j = 0; j < 8; ++j) a8[j] = 0.f;
            }
            bf16x8 afrag;
            #pragma unroll
            for (int j = 0; j < 8; ++j) {
                ss = fmaf(a8[j], a8[j], ss);
                ((unsigned short*)&afrag)[j] = f2bf(a8[j]);
            }
            const int cl = (s << 5) + (lg << 3);
            #pragma unroll
            for (int rt = 0; rt < 4; ++rt) {
                bf16x8 bfrag = *reinterpret_cast<const bf16x8*>(&Wb[(rt*16 + lr)*136 + cl]);
                acc[rt] = __builtin_amdgcn_mfma_f32_16x16x32_bf16(afrag, bfrag, acc[rt], 0, 0, 0);
            }
        }
        __syncthreads();
    }

    // ---- token norm: reduce the 4 lg-lanes of the same token ----
    ss += __shfl_xor(ss, 16);
    ss += __shfl_xor(ss, 32);
    const float nrm = sqrtf(ss);
    const float inv = 1.0f / fmaxf(nrm, EPSF);

    // ---- logits + softmax over 64 regions ----
    float b_[4];
    #pragma unroll
    for (int rt = 0; rt < 4; ++rt) b_[rt] = conv_b[rt*16 + lr];

    float invT[4];
    #pragma unroll
    for (int reg = 0; reg < 4; ++reg) invT[reg] = __shfl(inv, (lg << 2) + reg);

    float lgt[4][4], mx[4];
    #pragma unroll
    for (int reg = 0; reg < 4; ++reg) {
        float m = -1e30f;
        #pragma unroll
        for (int rt = 0; rt < 4; ++rt) {
            lgt[rt][reg] = fmaf(acc[rt][reg], invT[reg], b_[rt]);
            m = fmaxf(m, lgt[rt][reg]);
        }
        mx[reg] = m;
    }
    #pragma unroll
    for (int msk = 1; msk < 16; msk <<= 1) {
        #pragma unroll
        for (int reg = 0; reg < 4; ++reg) mx[reg] = fmaxf(mx[reg], __shfl_xor(mx[reg], msk));
    }
    float ex[4][4], sm[4] = {0.f, 0.f, 0.f, 0.f};
    #pragma unroll
    for (int rt = 0; rt < 4; ++rt) {
        #pragma unroll
        for (int reg = 0; reg < 4; ++reg) {
            ex[rt][reg] = __expf(lgt[rt][reg] - mx[reg]);
            sm[reg] += ex[rt][reg];
        }
    }
    #pragma unroll
    for (int msk = 1; msk < 16; msk <<= 1) {
        #pragma unroll
        for (int reg = 0; reg < 4; ++reg) sm[reg] += __shfl_xor(sm[reg], msk);
    }

    // masked reciprocal denominators (0 for padded tokens)
    float rsm[4];
    #pragma unroll
    for (int reg = 0; reg < 4; ++reg) {
        const bool vt = (t0w + (lg << 2) + reg) < TT;
        rsm[reg] = vt ? (1.0f / sm[reg]) : 0.f;
    }

    // ---- partial asum over this block: pa[rt] holds kr = rt*16+lr ----
    float pa[4];
    #pragma unroll
    for (int rt = 0; rt < 4; ++rt) {
        pa[rt] = ex[rt][0]*rsm[0] + ex[rt][1]*rsm[1] + ex[rt][2]*rsm[2] + ex[rt][3]*rsm[3];
        pa[rt] += __shfl_xor(pa[rt], 16);
        pa[rt] += __shfl_xor(pa[rt], 32);
    }
    float* asum_lds = reinterpret_cast<float*>(&Wl[1][0]);   // [4 waves][64 kr]
    if (lane < 16) {
        #pragma unroll
        for (int rt = 0; rt < 4; ++rt)
            asum_lds[(w << 6) + rt*16 + lane] = pa[rt];
    }

    // ---- a' = softmax * inv_norm, transposed via LDS (aliased on Wl[0]) ----
    unsigned short* Abuf = &Wl[0][0] + (size_t)w * KR * 24;
    #pragma unroll
    for (int reg = 0; reg < 4; ++reg) {
        const int trow = (lg << 2) + reg;
        const float scale = invT[reg] * rsm[reg];
        #pragma unroll
        for (int rt = 0; rt < 4; ++rt)
            Abuf[(rt*16 + lr)*24 + trow] = f2bf(ex[rt][reg] * scale);
    }
    __syncthreads();

    if (tid < 64)
        ws_asum[(size_t)blockIdx.x * 64 + tid] =
            asum_lds[tid] + asum_lds[64 + tid] + asum_lds[128 + tid] + asum_lds[192 + tid];

    {
        ushort8 r0 = *reinterpret_cast<const ushort8*>(&Abuf[lane * 24]);
        ushort8 r1 = *reinterpret_cast<const ushort8*>(&Abuf[lane * 24 + 8]);
        unsigned short* dst = ws_a + ((size_t)n * KR + lane) * TP + t0w;
        *reinterpret_cast<ushort8*>(dst)     = r0;
        *reinterpret_cast<ushort8*>(dst + 8) = r1;
    }
}

// ---------------------------------------------------------------------------
// Kernel 2: GEMM2 (VLAD): grid = n x 12 c-tiles (64 c) = 768 blocks, 4 waves,
// wave tile 64kr x 16c. No LDS staging. Ping-pong prefetch with NAMED
// fragment variables only (no pointer/reference selection -> no scratch).
// ---------------------------------------------------------------------------
#define LOADA(d0,d1,d2,d3,t0_)                                                   \
    d0 = *reinterpret_cast<const bf16x8*>(abase +            (size_t)(t0_));     \
    d1 = *reinterpret_cast<const bf16x8*>(abase + 16*TP +    (size_t)(t0_));     \
    d2 = *reinterpret_cast<const bf16x8*>(abase + 32*TP +    (size_t)(t0_));     \
    d3 = *reinterpret_cast<const bf16x8*>(abase + 48*TP +    (size_t)(t0_));

#define LOADB(d,t0_) do {                                                        \
    const int tb2_ = (t0_) + (lg << 3);                                          \
    if ((t0_) + 32 <= TT) {                                                      \
        _Pragma("unroll")                                                        \
        for (int j_ = 0; j_ < 8; ++j_)                                           \
            ((unsigned short*)&(d))[j_] = f2bf(gb[(size_t)(tb2_ + j_) * CCH]);   \
    } else {                                                                     \
        _Pragma("unroll")                                                        \
        for (int j_ = 0; j_ < 8; ++j_) {                                         \
            float v_ = (tb2_ + j_ < TT) ? gb[(size_t)(tb2_ + j_) * CCH] : 0.f;   \
            ((unsigned short*)&(d))[j_] = f2bf(v_);                              \
        }                                                                        \
    } } while (0)

__global__ __launch_bounds__(256) void k_vlad(
    const float* __restrict__ grids,
    const unsigned short* __restrict__ ws_a,
    const float* __restrict__ ws_asum,
    const float* __restrict__ centroids,
    float* __restrict__ out)
{
    __shared__ float asum_s[64];

    const int tid  = threadIdx.x;
    const int lane = tid & 63;
    const int w    = tid >> 6;
    const int n    = blockIdx.x / 12;
    const int c0   = (blockIdx.x - n * 12) << 6;
    const int lr   = lane & 15;
    const int lg   = lane >> 4;

    if (tid < 64) {
        float s = 0.f;
        #pragma unroll
        for (int b = 0; b < 10; ++b)
            s += ws_asum[((size_t)n * 10 + b) * 64 + tid];
        asum_s[tid] = s;
    }
    __syncthreads();

    const int c = c0 + (w << 4) + lr;
    const unsigned short* abase = ws_a + ((size_t)n * KR + lr) * TP + (lg << 3);
    const float* gb = grids + (size_t)n * TT * CCH + c;

    f32x4 acc0 = {}, acc1 = {}, acc2 = {}, acc3 = {};
    bf16x8 a0, a1, a2, a3, b0;
    bf16x8 p0, p1, p2, p3, q0;

    LOADA(a0, a1, a2, a3, 0)
    LOADB(b0, 0);

    int t0 = 0;
    while (true) {
        int tn = t0 + 32;
        if (tn < TT) { LOADA(p0, p1, p2, p3, tn) LOADB(q0, tn); }
        acc0 = __builtin_amdgcn_mfma_f32_16x16x32_bf16(a0, b0, acc0, 0, 0, 0);
        acc1 = __builtin_amdgcn_mfma_f32_16x16x32_bf16(a1, b0, acc1, 0, 0, 0);
        acc2 = __builtin_amdgcn_mfma_f32_16x16x32_bf16(a2, b0, acc2, 0, 0, 0);
        acc3 = __builtin_amdgcn_mfma_f32_16x16x32_bf16(a3, b0, acc3, 0, 0, 0);
        t0 = tn;
        if (t0 >= TT) break;

        tn = t0 + 32;
        if (tn < TT) { LOADA(a0, a1, a2, a3, tn) LOADB(b0, tn); }
        acc0 = __builtin_amdgcn_mfma_f32_16x16x32_bf16(p0, q0, acc0, 0, 0, 0);
        acc1 = __builtin_amdgcn_mfma_f32_16x16x32_bf16(p1, q0, acc1, 0, 0, 0);
        acc2 = __builtin_amdgcn_mfma_f32_16x16x32_bf16(p2, q0, acc2, 0, 0, 0);
        acc3 = __builtin_amdgcn_mfma_f32_16x16x32_bf16(p3, q0, acc3, 0, 0, 0);
        t0 = tn;
        if (t0 >= TT) break;
    }

    // ---- epilogue: subtract asum*centroid, write fp32 ----
    #pragma unroll
    for (int reg = 0; reg < 4; ++reg) {
        {
            const int kr = 0*16 + (lg << 2) + reg;
            out[((size_t)n * KR + kr) * CCH + c] =
                acc0[reg] - asum_s[kr] * centroids[(size_t)kr * CCH + c];
        }
        {
            const int kr = 1*16 + (lg << 2) + reg;
            out[((size_t)n * KR + kr) * CCH + c] =
                acc1[reg] - asum_s[kr] * centroids[(size_t)kr * CCH + c];
        }
        {
            const int kr = 2*16 + (lg << 2) + reg;
            out[((size_t)n * KR + kr) * CCH + c] =
                acc2[reg] - asum_s[kr] * centroids[(size_t)kr * CCH + c];
        }
        {
            const int kr = 3*16 + (lg << 2) + reg;
            out[((size_t)n * KR + kr) * CCH + c] =
                acc3[reg] - asum_s[kr] * centroids[(size_t)kr * CCH + c];
        }
    }
}

// ---------------------------------------------------------------------------
// Kernel 3: per (n,kr) row normalize; global L2 norm of 64 unit rows = 8.
// ---------------------------------------------------------------------------
__global__ __launch_bounds__(64) void kc_norm_kernel(float* __restrict__ out)
{
    float4* p = reinterpret_cast<float4*>(out) + (size_t)blockIdx.x * 192;
    const int l = threadIdx.x;
    float4 v0 = p[l];
    float4 v1 = p[l + 64];
    float4 v2 = p[l + 128];
    float ss = v0.x*v0.x + v0.y*v0.y + v0.z*v0.z + v0.w*v0.w
             + v1.x*v1.x + v1.y*v1.y + v1.z*v1.z + v1.w*v1.w
             + v2.x*v2.x + v2.y*v2.y + v2.z*v2.z + v2.w*v2.w;
    #pragma unroll
    for (int m = 1; m < 64; m <<= 1) ss += __shfl_xor(ss, m);
    const float sc = 0.125f / fmaxf(sqrtf(ss), EPSF);
    v0.x*=sc; v0.y*=sc; v0.z*=sc; v0.w*=sc;
    v1.x*=sc; v1.y*=sc; v1.z*=sc; v1.w*=sc;
    v2.x*=sc; v2.y*=sc; v2.z*=sc; v2.w*=sc;
    p[l] = v0;
    p[l + 64] = v1;
    p[l + 128] = v2;
}

extern "C" void kernel_launch(void* const* d_in, const int* in_sizes, int n_in,
                              void* d_out, int out_size, void* d_ws, size_t ws_size,
                              hipStream_t stream)
{
    const float* grids     = (const float*)d_in[0];
    const float* conv_w    = (const float*)d_in[1];
    const float* conv_b    = (const float*)d_in[2];
    const float* centroids = (const float*)d_in[3];
    float* out = (float*)d_out;

    unsigned short* ws_a = (unsigned short*)d_ws;                       // 64*64*640*2 = 5.24 MB
    float* ws_asum = (float*)((char*)d_ws + (size_t)NB * KR * TP * 2);  // 64*10*64*4 = 160 KB

    hipLaunchKernelGGL(k_logits, dim3(NB * 10), dim3(256), 0, stream,
                       grids, conv_w, conv_b, ws_a, ws_asum);
    hipLaunchKernelGGL(k_vlad, dim3(NB * 12), dim3(256), 0, stream,
                       grids, ws_a, ws_asum, centroids, out);
    hipLaunchKernelGGL(kc_norm_kernel, dim3(NB * KR), dim3(64), 0, stream, out);
}